// Round 1
// baseline (2672.962 us; speedup 1.0000x reference)
//
#include <hip/hip_runtime.h>
#include <hip/hip_bf16.h>

#define B_  16
#define T_  512
#define C_  1080
#define H_  20
#define HD_ 54
#define NQ_ ((size_t)B_ * H_ * T_ * HD_)

// ---------------------------------------------------------------------------
// Tiled fp32 GEMM: out[m][n] = sum_k A[m][k]*W[k][n] + bias[n]
// 64x64 tile, 256 threads, 4x4 micro-tile per thread, KT=16.
// mode 0: write [M][N] to outP.
// mode 1: scatter-write qkv: n -> (which, h, d), m -> (b, t); dst[b][h][t][d].
// ---------------------------------------------------------------------------
__global__ __launch_bounds__(256) void gemm64(
    const float* __restrict__ A, const float* __restrict__ W,
    const float* __restrict__ bias, int M, int N, int K, int mode,
    float* __restrict__ outP, float* __restrict__ outQ,
    float* __restrict__ outK, float* __restrict__ outV)
{
    __shared__ float As[16][64];   // As[k][m] (transposed stage)
    __shared__ float Bs[16][64];   // Bs[k][n]

    const int tid = threadIdx.x;
    const int m0 = blockIdx.y * 64;
    const int n0 = blockIdx.x * 64;
    const int tm = (tid >> 4) << 2;   // 0,4,8,12
    const int tn = (tid & 15) << 2;   // 0..60

    float acc[4][4] = {};

    for (int k0 = 0; k0 < K; k0 += 16) {
        // stage A tile: 64 rows x 16 cols -> As[col][row]
        #pragma unroll
        for (int i = tid; i < 1024; i += 256) {
            int r = i >> 4, c = i & 15;
            int kg = k0 + c;
            As[c][r] = (kg < K) ? A[(size_t)(m0 + r) * K + kg] : 0.f;
        }
        // stage B tile: 16 rows x 64 cols -> Bs[row][col]
        #pragma unroll
        for (int i = tid; i < 1024; i += 256) {
            int r = i >> 6, c = i & 63;
            int kg = k0 + r, ng = n0 + c;
            Bs[r][c] = (kg < K && ng < N) ? W[(size_t)kg * N + ng] : 0.f;
        }
        __syncthreads();

        #pragma unroll
        for (int kk = 0; kk < 16; ++kk) {
            float4 a4 = *reinterpret_cast<const float4*>(&As[kk][tm]);
            float4 b4 = *reinterpret_cast<const float4*>(&Bs[kk][tn]);
            float av[4] = {a4.x, a4.y, a4.z, a4.w};
            float bv[4] = {b4.x, b4.y, b4.z, b4.w};
            #pragma unroll
            for (int i = 0; i < 4; ++i)
                #pragma unroll
                for (int j = 0; j < 4; ++j)
                    acc[i][j] = fmaf(av[i], bv[j], acc[i][j]);
        }
        __syncthreads();
    }

    if (mode == 0) {
        #pragma unroll
        for (int i = 0; i < 4; ++i) {
            int m = m0 + tm + i;
            #pragma unroll
            for (int j = 0; j < 4; ++j) {
                int n = n0 + tn + j;
                if (n < N) outP[(size_t)m * N + n] = acc[i][j] + bias[n];
            }
        }
    } else {
        #pragma unroll
        for (int i = 0; i < 4; ++i) {
            int m = m0 + tm + i;
            int b = m / T_;
            int t = m - b * T_;
            #pragma unroll
            for (int j = 0; j < 4; ++j) {
                int n = n0 + tn + j;
                if (n < N) {
                    float val = acc[i][j] + bias[n];
                    int which = n / C_;
                    int c = n - which * C_;
                    int h = c / HD_;
                    int d = c - h * HD_;
                    float* dst = (which == 0) ? outQ : (which == 1) ? outK : outV;
                    dst[(((size_t)b * H_ + h) * T_ + t) * HD_ + d] = val;
                }
            }
        }
    }
}

// ---------------------------------------------------------------------------
// Flash-style causal attention.
// grid: (T/64 q-tiles, B*H). block: 256 threads = 64 q-rows x 4 lanes.
// Each 4-lane group owns one q-row: q in regs, online softmax (m,l) replicated,
// y accumulator split 14 d-elems per lane.
// ---------------------------------------------------------------------------
__global__ __launch_bounds__(256) void attn64(
    const float* __restrict__ Q, const float* __restrict__ Kp,
    const float* __restrict__ V, float* __restrict__ Y)
{
    __shared__ float ks[64][57];   // stride 57: conflict-spread
    __shared__ float vs[64][57];
    __shared__ float ps[64][65];   // stride 65: conflict-free p write/read

    const int tid = threadIdx.x;
    const int bh = blockIdx.y;            // b*H + h
    const int b  = bh / H_;
    const int h  = bh - b * H_;
    const int qt = blockIdx.x;
    const int qbase = qt * 64;
    const int row = tid >> 2;             // q-row within tile
    const int l4  = tid & 3;              // lane within 4-group

    // q row into registers (one-time, 4x redundant read, L2-served)
    float qreg[HD_];
    {
        const float* qp = Q + ((size_t)bh * T_ + qbase + row) * HD_;
        #pragma unroll
        for (int d = 0; d < HD_; ++d) qreg[d] = qp[d];
    }

    const float scale = 0.13608276348795434f;  // 1/sqrt(54)
    float m_run = -1e30f, l_run = 0.f;
    float acc[14] = {};

    for (int kt = 0; kt <= qt; ++kt) {
        const int kbase = kt * 64;
        const float* kp = Kp + ((size_t)bh * T_ + kbase) * HD_;
        const float* vp = V  + ((size_t)bh * T_ + kbase) * HD_;
        for (int i = tid; i < 64 * HD_; i += 256) {
            int r = i / HD_, c = i - r * HD_;
            ks[r][c] = kp[i];
            vs[r][c] = vp[i];
        }
        if (tid < 64) { vs[tid][54] = 0.f; vs[tid][55] = 0.f; vs[tid][56] = 0.f; }
        __syncthreads();

        // scores for this row: 16 k-columns per lane
        float sreg[16];
        float mloc = -1e30f;
        #pragma unroll
        for (int jj = 0; jj < 16; ++jj) {
            int kj = l4 + (jj << 2);
            float dot = 0.f;
            #pragma unroll
            for (int d = 0; d < HD_; ++d)
                dot = fmaf(qreg[d], ks[kj][d], dot);
            dot *= scale;
            if (kbase + kj > qbase + row) dot = -1e30f;   // causal mask
            sreg[jj] = dot;
            mloc = fmaxf(mloc, dot);
        }
        mloc = fmaxf(mloc, __shfl_xor(mloc, 1));
        mloc = fmaxf(mloc, __shfl_xor(mloc, 2));

        float m_new = fmaxf(m_run, mloc);
        float corr  = __expf(m_run - m_new);
        float lsum  = 0.f;
        #pragma unroll
        for (int jj = 0; jj < 16; ++jj) {
            float p = __expf(sreg[jj] - m_new);
            ps[row][l4 + (jj << 2)] = p;
            lsum += p;
        }
        lsum += __shfl_xor(lsum, 1);
        lsum += __shfl_xor(lsum, 2);
        l_run = l_run * corr + lsum;
        m_run = m_new;
        #pragma unroll
        for (int i = 0; i < 14; ++i) acc[i] *= corr;
        __syncthreads();

        // PV: y[d] += p[j] * v[j][d], d-quarter per lane
        #pragma unroll 4
        for (int j = 0; j < 64; ++j) {
            float p = ps[row][j];
            #pragma unroll
            for (int i = 0; i < 14; ++i)
                acc[i] = fmaf(p, vs[j][l4 * 14 + i], acc[i]);
        }
        __syncthreads();
    }

    const float inv = 1.f / l_run;
    const int t = qbase + row;
    #pragma unroll
    for (int i = 0; i < 14; ++i) {
        int d = l4 * 14 + i;
        if (d < HD_)
            Y[((size_t)b * T_ + t) * C_ + h * HD_ + d] = acc[i] * inv;
    }
}

// ---------------------------------------------------------------------------
extern "C" void kernel_launch(void* const* d_in, const int* in_sizes, int n_in,
                              void* d_out, int out_size, void* d_ws, size_t ws_size,
                              hipStream_t stream)
{
    const float* x      = (const float*)d_in[0];
    const float* W_attn = (const float*)d_in[1];
    const float* b_attn = (const float*)d_in[2];
    const float* W_proj = (const float*)d_in[3];
    const float* b_proj = (const float*)d_in[4];
    float* out = (float*)d_out;

    float* q = (float*)d_ws;           // [B,H,T,hd]
    float* k = q + NQ_;
    float* v = k + NQ_;
    float* y = v + NQ_;                // [B,T,C]

    const int M = B_ * T_;             // 8192
    dim3 blk(256);

    // 1) QKV projection, scatter into per-head layout
    dim3 g1((3 * C_ + 63) / 64, M / 64);
    gemm64<<<g1, blk, 0, stream>>>(x, W_attn, b_attn, M, 3 * C_, C_, 1,
                                   nullptr, q, k, v);

    // 2) causal flash attention -> y [B,T,C]
    dim3 g2(T_ / 64, B_ * H_);
    attn64<<<g2, blk, 0, stream>>>(q, k, v, y);

    // 3) output projection -> d_out
    dim3 g3((C_ + 63) / 64, M / 64);
    gemm64<<<g3, blk, 0, stream>>>(y, W_proj, b_proj, M, C_, C_, 0,
                                   out, nullptr, nullptr, nullptr);
}

// Round 2
// 1273.009 us; speedup vs baseline: 2.0997x; 2.0997x over previous
//
#include <hip/hip_runtime.h>
#include <hip/hip_bf16.h>

#define B_  16
#define T_  512
#define C_  1080
#define H_  20
#define HD_ 54
#define M_  (B_ * T_)          // 8192
#define KP_ 1088               // padded K (17*64)
#define NP_QKV_ 3328           // padded 3*C (26*128)
#define NP_PRJ_ 1152           // padded C  (9*128)

typedef short bf16x8 __attribute__((ext_vector_type(8)));
typedef float f32x4  __attribute__((ext_vector_type(4)));

__device__ __forceinline__ void gload_lds16(const void* g, void* l) {
    __builtin_amdgcn_global_load_lds(
        (const __attribute__((address_space(1))) void*)g,
        (__attribute__((address_space(3))) void*)l,
        16, 0, 0);
}

// ---------------------------------------------------------------------------
// x [8192][1080] fp32 -> xb [8192][1088] bf16, zero-padded. float4 in, ushort4 out.
// ---------------------------------------------------------------------------
__global__ __launch_bounds__(256) void cvt_pad(
    const float* __restrict__ src, __hip_bfloat16* __restrict__ dst)
{
    int idx = blockIdx.x * 256 + threadIdx.x;       // 8192 * 272 chunks
    if (idx >= M_ * (KP_ / 4)) return;
    int m = idx / (KP_ / 4), c = idx - m * (KP_ / 4);
    ushort4 o;
    if (c < C_ / 4) {
        float4 v = *reinterpret_cast<const float4*>(src + (size_t)m * C_ + c * 4);
        o.x = __builtin_bit_cast(unsigned short, __float2bfloat16(v.x));
        o.y = __builtin_bit_cast(unsigned short, __float2bfloat16(v.y));
        o.z = __builtin_bit_cast(unsigned short, __float2bfloat16(v.z));
        o.w = __builtin_bit_cast(unsigned short, __float2bfloat16(v.w));
    } else {
        o.x = o.y = o.z = o.w = 0;
    }
    *reinterpret_cast<ushort4*>(reinterpret_cast<unsigned short*>(dst) + (size_t)m * KP_ + c * 4) = o;
}

// ---------------------------------------------------------------------------
// W [K][N] fp32 -> Wt [Np][Kp] bf16 (transposed, zero-padded). 32x32 LDS tile.
// ---------------------------------------------------------------------------
__global__ __launch_bounds__(256) void transpose_w(
    const float* __restrict__ W, __hip_bfloat16* __restrict__ Wt,
    int K, int N, int Kp, int Np)
{
    __shared__ float tile[32][33];
    int n0 = blockIdx.x * 32, k0 = blockIdx.y * 32;
    int tx = threadIdx.x, ty = threadIdx.y;
    #pragma unroll
    for (int i = 0; i < 32; i += 8) {
        int k = k0 + ty + i, n = n0 + tx;
        tile[ty + i][tx] = (k < K && n < N) ? W[(size_t)k * N + n] : 0.f;
    }
    __syncthreads();
    #pragma unroll
    for (int i = 0; i < 32; i += 8) {
        int n = n0 + ty + i, k = k0 + tx;
        Wt[(size_t)n * Kp + k] = __float2bfloat16(tile[tx][ty + i]);
    }
}

// ---------------------------------------------------------------------------
// zero yb[:, 1080:1088]
// ---------------------------------------------------------------------------
__global__ __launch_bounds__(256) void pad_yb(__hip_bfloat16* __restrict__ yb)
{
    int i = blockIdx.x * 256 + threadIdx.x;          // 8192*8
    if (i < M_ * 8) {
        int m = i >> 3, c = i & 7;
        yb[(size_t)m * KP_ + C_ + c] = __float2bfloat16(0.f);
    }
}

// ---------------------------------------------------------------------------
// bf16 MFMA GEMM, m97 structure: 128x128 tile, BK=64, 4 waves, each wave a
// 64x64 sub-tile of 4x4 16x16x32 fragments. global_load_lds(16B) staging with
// pre-swizzled source; XOR-swizzled ds_read_b128 (bank-conflict-free).
// A [M][KP_] bf16, Bt [Np][KP_] bf16 (B transposed, k-contiguous).
// MODE 0: outP[m*1080+n] = acc + bias[n]  (fp32)
// MODE 1: scatter qkv -> q/k/v [B][H][T][54] bf16
// ---------------------------------------------------------------------------
template<int MODE>
__global__ __launch_bounds__(256) void gemm_mfma(
    const unsigned short* __restrict__ A,
    const unsigned short* __restrict__ Bt,
    const float* __restrict__ bias,
    float* __restrict__ outP,
    __hip_bfloat16* __restrict__ outQ,
    __hip_bfloat16* __restrict__ outK,
    __hip_bfloat16* __restrict__ outV)
{
    __shared__ __align__(16) char smem[32768];       // A tile 16K | B tile 16K

    const int tid  = threadIdx.x;
    const int lane = tid & 63;
    const int wv   = tid >> 6;
    const int wm   = (wv >> 1) * 64;
    const int wn   = (wv & 1) * 64;
    const int lr   = lane & 15;                      // frag row (A) / col (B,C)
    const int lk   = lane >> 4;                      // 0..3

    const int m0 = blockIdx.y * 128;
    const int n0 = blockIdx.x * 128;

    f32x4 acc[4][4] = {};

    for (int k0 = 0; k0 < KP_; k0 += 64) {
        // stage A tile 128x64 (16KB): lane-linear LDS dest, source k-chunk
        // pre-swizzled by p ^ (row&7) so swizzled reads see linear data.
        #pragma unroll
        for (int it = 0; it < 4; ++it) {
            int ci = it * 256 + tid;                 // 16B-chunk index 0..1023
            int r  = ci >> 3, p = ci & 7;
            int kc = p ^ (r & 7);
            gload_lds16(A + (size_t)(m0 + r) * KP_ + k0 + kc * 8, smem + ci * 16);
        }
        #pragma unroll
        for (int it = 0; it < 4; ++it) {
            int ci = it * 256 + tid;
            int r  = ci >> 3, p = ci & 7;
            int kc = p ^ (r & 7);
            gload_lds16(Bt + (size_t)(n0 + r) * KP_ + k0 + kc * 8, smem + 16384 + ci * 16);
        }
        __syncthreads();

        #pragma unroll
        for (int kk = 0; kk < 2; ++kk) {
            bf16x8 af[4], bfr[4];
            #pragma unroll
            for (int mi = 0; mi < 4; ++mi) {
                int row = wm + mi * 16 + lr;
                int cp  = (kk * 4 + lk) ^ (row & 7);
                af[mi] = *reinterpret_cast<const bf16x8*>(smem + row * 128 + cp * 16);
            }
            #pragma unroll
            for (int ni = 0; ni < 4; ++ni) {
                int row = wn + ni * 16 + lr;
                int cp  = (kk * 4 + lk) ^ (row & 7);
                bfr[ni] = *reinterpret_cast<const bf16x8*>(smem + 16384 + row * 128 + cp * 16);
            }
            #pragma unroll
            for (int mi = 0; mi < 4; ++mi)
                #pragma unroll
                for (int ni = 0; ni < 4; ++ni)
                    acc[mi][ni] = __builtin_amdgcn_mfma_f32_16x16x32_bf16(
                        af[mi], bfr[ni], acc[mi][ni], 0, 0, 0);
        }
        __syncthreads();
    }

    // epilogue: C frag layout col = lane&15, row = (lane>>4)*4 + j
    if constexpr (MODE == 0) {
        #pragma unroll
        for (int mi = 0; mi < 4; ++mi) {
            int mrow = m0 + wm + mi * 16 + lk * 4;
            #pragma unroll
            for (int ni = 0; ni < 4; ++ni) {
                int n = n0 + wn + ni * 16 + lr;
                if (n < C_) {
                    float bs = bias[n];
                    #pragma unroll
                    for (int j = 0; j < 4; ++j)
                        outP[(size_t)(mrow + j) * C_ + n] = acc[mi][ni][j] + bs;
                }
            }
        }
    } else {
        #pragma unroll
        for (int mi = 0; mi < 4; ++mi) {
            int mrow = m0 + wm + mi * 16 + lk * 4;
            #pragma unroll
            for (int ni = 0; ni < 4; ++ni) {
                int n = n0 + wn + ni * 16 + lr;
                if (n < 3 * C_) {
                    int which = n / C_;
                    int c2 = n - which * C_;
                    int h  = c2 / HD_;
                    int d  = c2 - h * HD_;
                    float bs = bias[n];
                    __hip_bfloat16* dst = (which == 0) ? outQ : (which == 1) ? outK : outV;
                    #pragma unroll
                    for (int j = 0; j < 4; ++j) {
                        int m = mrow + j;
                        int b = m >> 9, t = m & (T_ - 1);
                        dst[(((size_t)b * H_ + h) * T_ + t) * HD_ + d] =
                            __float2bfloat16(acc[mi][ni][j] + bs);
                    }
                }
            }
        }
    }
}

// ---------------------------------------------------------------------------
// Flash-style causal attention (fp32 compute, bf16 in/out).
// grid: (T/64, B*H). 256 threads = 64 q-rows x 4 lanes.
// ---------------------------------------------------------------------------
__global__ __launch_bounds__(256) void attn64(
    const __hip_bfloat16* __restrict__ Q, const __hip_bfloat16* __restrict__ Kp,
    const __hip_bfloat16* __restrict__ V, __hip_bfloat16* __restrict__ Y)
{
    __shared__ float ks[64][57];
    __shared__ float vs[64][57];
    __shared__ float ps[64][65];

    const int tid = threadIdx.x;
    const int bh = blockIdx.y;
    const int qt = blockIdx.x;
    const int qbase = qt * 64;
    const int row = tid >> 2;
    const int l4  = tid & 3;

    float qreg[HD_];
    {
        const __hip_bfloat16* qp = Q + ((size_t)bh * T_ + qbase + row) * HD_;
        #pragma unroll
        for (int d = 0; d < HD_; ++d) qreg[d] = __bfloat162float(qp[d]);
    }

    const float scale = 0.13608276348795434f;  // 1/sqrt(54)
    float m_run = -1e30f, l_run = 0.f;
    float acc[14] = {};

    for (int kt = 0; kt <= qt; ++kt) {
        const int kbase = kt * 64;
        const __hip_bfloat16* kp = Kp + ((size_t)bh * T_ + kbase) * HD_;
        const __hip_bfloat16* vp = V  + ((size_t)bh * T_ + kbase) * HD_;
        for (int i = tid; i < 64 * HD_; i += 256) {
            int r = i / HD_, c = i - r * HD_;
            ks[r][c] = __bfloat162float(kp[i]);
            vs[r][c] = __bfloat162float(vp[i]);
        }
        if (tid < 64) { vs[tid][54] = 0.f; vs[tid][55] = 0.f; vs[tid][56] = 0.f; }
        __syncthreads();

        float sreg[16];
        float mloc = -1e30f;
        #pragma unroll
        for (int jj = 0; jj < 16; ++jj) {
            int kj = l4 + (jj << 2);
            float dot = 0.f;
            #pragma unroll
            for (int d = 0; d < HD_; ++d)
                dot = fmaf(qreg[d], ks[kj][d], dot);
            dot *= scale;
            if (kbase + kj > qbase + row) dot = -1e30f;
            sreg[jj] = dot;
            mloc = fmaxf(mloc, dot);
        }
        mloc = fmaxf(mloc, __shfl_xor(mloc, 1));
        mloc = fmaxf(mloc, __shfl_xor(mloc, 2));

        float m_new = fmaxf(m_run, mloc);
        float corr  = __expf(m_run - m_new);
        float lsum  = 0.f;
        #pragma unroll
        for (int jj = 0; jj < 16; ++jj) {
            float p = __expf(sreg[jj] - m_new);
            ps[row][l4 + (jj << 2)] = p;
            lsum += p;
        }
        lsum += __shfl_xor(lsum, 1);
        lsum += __shfl_xor(lsum, 2);
        l_run = l_run * corr + lsum;
        m_run = m_new;
        #pragma unroll
        for (int i = 0; i < 14; ++i) acc[i] *= corr;
        __syncthreads();

        #pragma unroll 4
        for (int j = 0; j < 64; ++j) {
            float p = ps[row][j];
            #pragma unroll
            for (int i = 0; i < 14; ++i)
                acc[i] = fmaf(p, vs[j][l4 * 14 + i], acc[i]);
        }
        __syncthreads();
    }

    const float inv = 1.f / l_run;
    const int m = bh / H_ * T_ + (qbase + row);      // b*T + t
    const int h = bh % H_;
    #pragma unroll
    for (int i = 0; i < 14; ++i) {
        int d = l4 * 14 + i;
        if (d < HD_)
            Y[(size_t)m * KP_ + h * HD_ + d] = __float2bfloat16(acc[i] * inv);
    }
}

// ---------------------------------------------------------------------------
extern "C" void kernel_launch(void* const* d_in, const int* in_sizes, int n_in,
                              void* d_out, int out_size, void* d_ws, size_t ws_size,
                              hipStream_t stream)
{
    const float* x      = (const float*)d_in[0];
    const float* W_attn = (const float*)d_in[1];
    const float* b_attn = (const float*)d_in[2];
    const float* W_proj = (const float*)d_in[3];
    const float* b_proj = (const float*)d_in[4];
    float* out = (float*)d_out;

    __hip_bfloat16* xb  = (__hip_bfloat16*)d_ws;       // [8192][1088]
    __hip_bfloat16* yb  = xb  + (size_t)M_ * KP_;      // [8192][1088]
    __hip_bfloat16* qb  = yb  + (size_t)M_ * KP_;      // [B][H][T][54]
    __hip_bfloat16* kb  = qb  + (size_t)B_ * H_ * T_ * HD_;
    __hip_bfloat16* vb  = kb  + (size_t)B_ * H_ * T_ * HD_;
    __hip_bfloat16* wta = vb  + (size_t)B_ * H_ * T_ * HD_;  // [3328][1088]
    __hip_bfloat16* wtp = wta + (size_t)NP_QKV_ * KP_;       // [1152][1088]

    // conversions / transposes
    cvt_pad<<<(M_ * (KP_ / 4) + 255) / 256, 256, 0, stream>>>(x, xb);
    transpose_w<<<dim3(NP_QKV_ / 32, KP_ / 32), dim3(32, 8), 0, stream>>>(
        W_attn, wta, C_, 3 * C_, KP_, NP_QKV_);
    transpose_w<<<dim3(NP_PRJ_ / 32, KP_ / 32), dim3(32, 8), 0, stream>>>(
        W_proj, wtp, C_, C_, KP_, NP_PRJ_);

    // 1) QKV projection (bf16 MFMA), scatter into per-head layout
    gemm_mfma<1><<<dim3(NP_QKV_ / 128, M_ / 128), 256, 0, stream>>>(
        (const unsigned short*)xb, (const unsigned short*)wta, b_attn,
        nullptr, qb, kb, vb);

    // 2) causal flash attention -> yb [8192][1088] bf16 (+ pad zeroing)
    attn64<<<dim3(T_ / 64, B_ * H_), 256, 0, stream>>>(qb, kb, vb, yb);
    pad_yb<<<(M_ * 8 + 255) / 256, 256, 0, stream>>>(yb);

    // 3) output projection (bf16 MFMA) -> d_out fp32
    gemm_mfma<0><<<dim3(NP_PRJ_ / 128, M_ / 128), 256, 0, stream>>>(
        (const unsigned short*)yb, (const unsigned short*)wtp, b_proj,
        out, nullptr, nullptr, nullptr);
}

// Round 3
// 269.141 us; speedup vs baseline: 9.9315x; 4.7299x over previous
//
#include <hip/hip_runtime.h>
#include <hip/hip_bf16.h>

#define B_  16
#define T_  512
#define C_  1080
#define H_  20
#define HD_ 54
#define DP_ 64                 // padded head dim
#define M_  (B_ * T_)          // 8192
#define KP_ 1088               // padded K (17*64)
#define NP_QKV_ 3328           // padded 3*C (26*128)
#define NP_PRJ_ 1152           // padded C  (9*128)
#define NBT_ (B_ * H_ * T_)    // 163840

typedef short bf16x8 __attribute__((ext_vector_type(8)));
typedef float f32x4  __attribute__((ext_vector_type(4)));

__device__ __forceinline__ void gload_lds16(const void* g, void* l) {
    __builtin_amdgcn_global_load_lds(
        (const __attribute__((address_space(1))) void*)g,
        (__attribute__((address_space(3))) void*)l,
        16, 0, 0);
}

// ---------------------------------------------------------------------------
// x [8192][1080] fp32 -> xb [8192][1088] bf16, zero-padded.
// ---------------------------------------------------------------------------
__global__ __launch_bounds__(256) void cvt_pad(
    const float* __restrict__ src, __hip_bfloat16* __restrict__ dst)
{
    int idx = blockIdx.x * 256 + threadIdx.x;
    if (idx >= M_ * (KP_ / 4)) return;
    int m = idx / (KP_ / 4), c = idx - m * (KP_ / 4);
    ushort4 o;
    if (c < C_ / 4) {
        float4 v = *reinterpret_cast<const float4*>(src + (size_t)m * C_ + c * 4);
        o.x = __builtin_bit_cast(unsigned short, __float2bfloat16(v.x));
        o.y = __builtin_bit_cast(unsigned short, __float2bfloat16(v.y));
        o.z = __builtin_bit_cast(unsigned short, __float2bfloat16(v.z));
        o.w = __builtin_bit_cast(unsigned short, __float2bfloat16(v.w));
    } else {
        o.x = o.y = o.z = o.w = 0;
    }
    *reinterpret_cast<ushort4*>(reinterpret_cast<unsigned short*>(dst) + (size_t)m * KP_ + c * 4) = o;
}

// ---------------------------------------------------------------------------
// W [K][N] fp32 -> Wt [Np][Kp] bf16 (transposed, zero-padded).
// ---------------------------------------------------------------------------
__global__ __launch_bounds__(256) void transpose_w(
    const float* __restrict__ W, __hip_bfloat16* __restrict__ Wt,
    int K, int N, int Kp, int Np)
{
    __shared__ float tile[32][33];
    int n0 = blockIdx.x * 32, k0 = blockIdx.y * 32;
    int tx = threadIdx.x, ty = threadIdx.y;
    #pragma unroll
    for (int i = 0; i < 32; i += 8) {
        int k = k0 + ty + i, n = n0 + tx;
        tile[ty + i][tx] = (k < K && n < N) ? W[(size_t)k * N + n] : 0.f;
    }
    __syncthreads();
    #pragma unroll
    for (int i = 0; i < 32; i += 8) {
        int n = n0 + ty + i, k = k0 + tx;
        Wt[(size_t)n * Kp + k] = __float2bfloat16(tile[tx][ty + i]);
    }
}

// ---------------------------------------------------------------------------
// zero the d=54..63 pads of q/k ([bh][t][64]) and vt ([bh][64][t]).
// ---------------------------------------------------------------------------
__global__ __launch_bounds__(256) void pad_qkv(
    unsigned short* __restrict__ qb, unsigned short* __restrict__ kb,
    unsigned short* __restrict__ vt)
{
    int i = blockIdx.x * 256 + threadIdx.x;
    if (i < NBT_ * 10) {
        int bt = i / 10, d = 54 + (i - bt * 10);
        qb[(size_t)bt * DP_ + d] = 0;
        kb[(size_t)bt * DP_ + d] = 0;
        int bh = bt / T_, t = bt - bh * T_;
        vt[((size_t)bh * DP_ + d) * T_ + t] = 0;
    }
}

// ---------------------------------------------------------------------------
// bf16 MFMA GEMM (m97 structure): 128x128 tile, BK=64, 4 waves.
// MODE 0: outP[m*1080+n] = acc + bias[n]  (fp32)
// MODE 1: scatter qkv: q,k -> [bh][t][64]; v -> transposed [bh][64][t]
// ---------------------------------------------------------------------------
template<int MODE>
__global__ __launch_bounds__(256) void gemm_mfma(
    const unsigned short* __restrict__ A,
    const unsigned short* __restrict__ Bt,
    const float* __restrict__ bias,
    float* __restrict__ outP,
    unsigned short* __restrict__ outQ,
    unsigned short* __restrict__ outK,
    unsigned short* __restrict__ outV)
{
    __shared__ __align__(16) char smem[32768];

    const int tid  = threadIdx.x;
    const int lane = tid & 63;
    const int wv   = tid >> 6;
    const int wm   = (wv >> 1) * 64;
    const int wn   = (wv & 1) * 64;
    const int lr   = lane & 15;
    const int lk   = lane >> 4;

    const int m0 = blockIdx.y * 128;
    const int n0 = blockIdx.x * 128;

    f32x4 acc[4][4] = {};

    for (int k0 = 0; k0 < KP_; k0 += 64) {
        #pragma unroll
        for (int it = 0; it < 4; ++it) {
            int ci = it * 256 + tid;
            int r  = ci >> 3, p = ci & 7;
            int kc = p ^ (r & 7);
            gload_lds16(A + (size_t)(m0 + r) * KP_ + k0 + kc * 8, smem + ci * 16);
        }
        #pragma unroll
        for (int it = 0; it < 4; ++it) {
            int ci = it * 256 + tid;
            int r  = ci >> 3, p = ci & 7;
            int kc = p ^ (r & 7);
            gload_lds16(Bt + (size_t)(n0 + r) * KP_ + k0 + kc * 8, smem + 16384 + ci * 16);
        }
        __syncthreads();

        #pragma unroll
        for (int kk = 0; kk < 2; ++kk) {
            bf16x8 af[4], bfr[4];
            #pragma unroll
            for (int mi = 0; mi < 4; ++mi) {
                int row = wm + mi * 16 + lr;
                int cp  = (kk * 4 + lk) ^ (row & 7);
                af[mi] = *reinterpret_cast<const bf16x8*>(smem + row * 128 + cp * 16);
            }
            #pragma unroll
            for (int ni = 0; ni < 4; ++ni) {
                int row = wn + ni * 16 + lr;
                int cp  = (kk * 4 + lk) ^ (row & 7);
                bfr[ni] = *reinterpret_cast<const bf16x8*>(smem + 16384 + row * 128 + cp * 16);
            }
            #pragma unroll
            for (int mi = 0; mi < 4; ++mi)
                #pragma unroll
                for (int ni = 0; ni < 4; ++ni)
                    acc[mi][ni] = __builtin_amdgcn_mfma_f32_16x16x32_bf16(
                        af[mi], bfr[ni], acc[mi][ni], 0, 0, 0);
        }
        __syncthreads();
    }

    if constexpr (MODE == 0) {
        #pragma unroll
        for (int mi = 0; mi < 4; ++mi) {
            int mrow = m0 + wm + mi * 16 + lk * 4;
            #pragma unroll
            for (int ni = 0; ni < 4; ++ni) {
                int n = n0 + wn + ni * 16 + lr;
                if (n < C_) {
                    float bs = bias[n];
                    #pragma unroll
                    for (int j = 0; j < 4; ++j)
                        outP[(size_t)(mrow + j) * C_ + n] = acc[mi][ni][j] + bs;
                }
            }
        }
    } else {
        #pragma unroll
        for (int mi = 0; mi < 4; ++mi) {
            int mrow = m0 + wm + mi * 16 + lk * 4;
            #pragma unroll
            for (int ni = 0; ni < 4; ++ni) {
                int n = n0 + wn + ni * 16 + lr;
                if (n < 3 * C_) {
                    int which = n / C_;
                    int c2 = n - which * C_;
                    int h  = c2 / HD_;
                    int d  = c2 - h * HD_;
                    float bs = bias[n];
                    #pragma unroll
                    for (int j = 0; j < 4; ++j) {
                        int m = mrow + j;
                        int b = m >> 9, t = m & (T_ - 1);
                        size_t bh = (size_t)b * H_ + h;
                        unsigned short val = __builtin_bit_cast(unsigned short,
                            __float2bfloat16(acc[mi][ni][j] + bs));
                        if (which == 0)      outQ[(bh * T_ + t) * DP_ + d] = val;
                        else if (which == 1) outK[(bh * T_ + t) * DP_ + d] = val;
                        else                 outV[(bh * DP_ + d) * T_ + t] = val;
                    }
                }
            }
        }
    }
}

// ---------------------------------------------------------------------------
// MFMA flash attention. grid: (T/64, B*H). 256 threads = 4 waves x 16 q-rows.
// Q,K: [bh][t][64] bf16; Vt: [bh][64][t] bf16; Y: [b*T][1088] bf16.
// Fragment conventions (verified by the GEMM): A row = lane&15, 8-contig k at
// 8*(lane>>4); B col = lane&15; C col = lane&15, row = (lane>>4)*4+j.
// ---------------------------------------------------------------------------
__global__ __launch_bounds__(256) void attn_mfma(
    const unsigned short* __restrict__ Q, const unsigned short* __restrict__ K,
    const unsigned short* __restrict__ Vt, __hip_bfloat16* __restrict__ Y)
{
    __shared__ __align__(16) char kvs[16384];               // K tile | Vt tile
    __shared__ __align__(16) unsigned short ps[4][16][72];  // per-wave P, swizzled

    const int tid  = threadIdx.x;
    const int lane = tid & 63;
    const int wv   = tid >> 6;
    const int lq   = lane & 15;
    const int lg   = lane >> 4;
    const int bh   = blockIdx.y;
    const int qt   = blockIdx.x;
    const int qbase = qt * 64;
    const float scale = 0.13608276348795434f;  // 1/sqrt(54)

    // Q fragments (A-layout), loaded once
    bf16x8 qf[2];
    {
        const unsigned short* qp = Q + ((size_t)bh * T_ + qbase + wv * 16 + lq) * DP_;
        qf[0] = *reinterpret_cast<const bf16x8*>(qp + lg * 8);
        qf[1] = *reinterpret_cast<const bf16x8*>(qp + 32 + lg * 8);
    }

    f32x4 o[4] = {};
    f32x4 m_run, l_run;
    #pragma unroll
    for (int j = 0; j < 4; ++j) { m_run[j] = -3.0e38f; l_run[j] = 0.f; }

    unsigned short* pbase = &ps[wv][0][0];

    const int nt = qt + 1;
    for (int kt = 0; kt < nt; ++kt) {
        const int kbase = kt * 64;
        // stage K [64 kv][64 d] and Vt [64 d][64 kv] (swizzled src, linear dst)
        {
            const unsigned short* kgp = K  + ((size_t)bh * T_ + kbase) * DP_;
            const unsigned short* vgp = Vt + (size_t)bh * DP_ * T_ + kbase;
            #pragma unroll
            for (int it = 0; it < 2; ++it) {
                int ci = it * 256 + tid;
                int r = ci >> 3, p = ci & 7;
                int pc = p ^ (r & 7);
                gload_lds16(kgp + (size_t)r * DP_ + pc * 8, kvs + ci * 16);
            }
            #pragma unroll
            for (int it = 0; it < 2; ++it) {
                int ci = it * 256 + tid;
                int r = ci >> 3, p = ci & 7;
                int pc = p ^ (r & 7);
                gload_lds16(vgp + (size_t)r * T_ + pc * 8, kvs + 8192 + ci * 16);
            }
        }
        __syncthreads();

        // QK^T: s[ni] (16 q x 16 k), k-col = ni*16+lq, q-row = lg*4+j
        f32x4 s[4] = {};
        #pragma unroll
        for (int dc = 0; dc < 2; ++dc) {
            #pragma unroll
            for (int ni = 0; ni < 4; ++ni) {
                int row = ni * 16 + lq;
                int ch  = (dc * 4 + lg) ^ (row & 7);
                bf16x8 kf = *reinterpret_cast<const bf16x8*>(kvs + row * 128 + ch * 16);
                s[ni] = __builtin_amdgcn_mfma_f32_16x16x32_bf16(qf[dc], kf, s[ni], 0, 0, 0);
            }
        }

        // scale + causal mask + row max
        f32x4 mloc;
        #pragma unroll
        for (int j = 0; j < 4; ++j) mloc[j] = -3.0e38f;
        #pragma unroll
        for (int ni = 0; ni < 4; ++ni) {
            int kg = kbase + ni * 16 + lq;
            #pragma unroll
            for (int j = 0; j < 4; ++j) {
                int qg = qbase + wv * 16 + lg * 4 + j;
                float sv = s[ni][j] * scale;
                sv = (kg > qg) ? -3.0e38f : sv;
                s[ni][j] = sv;
                mloc[j] = fmaxf(mloc[j], sv);
            }
        }
        #pragma unroll
        for (int x = 1; x < 16; x <<= 1)
            #pragma unroll
            for (int j = 0; j < 4; ++j)
                mloc[j] = fmaxf(mloc[j], __shfl_xor(mloc[j], x));

        f32x4 corr, lsum;
        #pragma unroll
        for (int j = 0; j < 4; ++j) {
            float mn = fmaxf(m_run[j], mloc[j]);
            corr[j]  = __expf(m_run[j] - mn);
            m_run[j] = mn;
            lsum[j]  = 0.f;
        }
        // P = exp(s - m), write bf16 to per-wave LDS (chunk-XOR swizzled rows)
        #pragma unroll
        for (int ni = 0; ni < 4; ++ni) {
            #pragma unroll
            for (int j = 0; j < 4; ++j) {
                float p = __expf(s[ni][j] - m_run[j]);
                lsum[j] += p;
                int qr = lg * 4 + j;
                int cidx = (ni * 2 + (lq >> 3)) ^ (qr & 7);
                pbase[qr * 72 + cidx * 8 + (lq & 7)] =
                    __builtin_bit_cast(unsigned short, __float2bfloat16(p));
            }
        }
        #pragma unroll
        for (int x = 1; x < 16; x <<= 1)
            #pragma unroll
            for (int j = 0; j < 4; ++j)
                lsum[j] += __shfl_xor(lsum[j], x);
        #pragma unroll
        for (int j = 0; j < 4; ++j)
            l_run[j] = l_run[j] * corr[j] + lsum[j];
        #pragma unroll
        for (int ni = 0; ni < 4; ++ni)
            #pragma unroll
            for (int j = 0; j < 4; ++j)
                o[ni][j] *= corr[j];

        // wave-local: ensure P writes landed before P reads
        asm volatile("s_waitcnt lgkmcnt(0)" ::: "memory");
        __builtin_amdgcn_sched_barrier(0);

        // PV: o[ni] += P[16q][64kv] x V[64kv][64d]
        #pragma unroll
        for (int dc = 0; dc < 2; ++dc) {
            int cc = (dc * 4 + lg) ^ (lq & 7);
            bf16x8 pf = *reinterpret_cast<const bf16x8*>(pbase + lq * 72 + cc * 8);
            #pragma unroll
            for (int ni = 0; ni < 4; ++ni) {
                int row = ni * 16 + lq;
                int ch  = (dc * 4 + lg) ^ (row & 7);
                bf16x8 vf = *reinterpret_cast<const bf16x8*>(kvs + 8192 + row * 128 + ch * 16);
                o[ni] = __builtin_amdgcn_mfma_f32_16x16x32_bf16(pf, vf, o[ni], 0, 0, 0);
            }
        }
        __syncthreads();
    }

    // normalize + write y [b*T][1088] at col h*54+d
    const int b = bh / H_, h = bh - b * H_;
    #pragma unroll
    for (int j = 0; j < 4; ++j) {
        float inv = 1.f / l_run[j];
        int t = qbase + wv * 16 + lg * 4 + j;
        #pragma unroll
        for (int ni = 0; ni < 4; ++ni) {
            int d = ni * 16 + lq;
            if (d < HD_)
                Y[((size_t)b * T_ + t) * KP_ + h * HD_ + d] =
                    __float2bfloat16(o[ni][j] * inv);
        }
    }
}

// ---------------------------------------------------------------------------
extern "C" void kernel_launch(void* const* d_in, const int* in_sizes, int n_in,
                              void* d_out, int out_size, void* d_ws, size_t ws_size,
                              hipStream_t stream)
{
    const float* x      = (const float*)d_in[0];
    const float* W_attn = (const float*)d_in[1];
    const float* b_attn = (const float*)d_in[2];
    const float* W_proj = (const float*)d_in[3];
    const float* b_proj = (const float*)d_in[4];
    float* out = (float*)d_out;

    // workspace layout (yb aliases xb: x is fully consumed before attn writes y)
    __hip_bfloat16* xb = (__hip_bfloat16*)d_ws;              // [8192][1088]
    unsigned short* qb = (unsigned short*)(xb + (size_t)M_ * KP_);   // [bh][t][64]
    unsigned short* kb = qb + (size_t)NBT_ * DP_;
    unsigned short* vtb = kb + (size_t)NBT_ * DP_;                   // [bh][64][t]
    __hip_bfloat16* wta = (__hip_bfloat16*)(vtb + (size_t)NBT_ * DP_); // [3328][1088]
    __hip_bfloat16* wtp = wta + (size_t)NP_QKV_ * KP_;               // [1152][1088]
    __hip_bfloat16* yb = xb;   // alias

    cvt_pad<<<(M_ * (KP_ / 4) + 255) / 256, 256, 0, stream>>>(x, xb);
    transpose_w<<<dim3(NP_QKV_ / 32, KP_ / 32), dim3(32, 8), 0, stream>>>(
        W_attn, wta, C_, 3 * C_, KP_, NP_QKV_);
    transpose_w<<<dim3(NP_PRJ_ / 32, KP_ / 32), dim3(32, 8), 0, stream>>>(
        W_proj, wtp, C_, C_, KP_, NP_PRJ_);
    pad_qkv<<<(NBT_ * 10 + 255) / 256, 256, 0, stream>>>(qb, kb, vtb);

    // 1) QKV projection -> q/k (padded), v transposed
    gemm_mfma<1><<<dim3(NP_QKV_ / 128, M_ / 128), 256, 0, stream>>>(
        (const unsigned short*)xb, (const unsigned short*)wta, b_attn,
        nullptr, qb, kb, vtb);

    // 2) MFMA flash attention -> yb (= xb; pad cols already zero from cvt_pad)
    attn_mfma<<<dim3(T_ / 64, B_ * H_), 256, 0, stream>>>(qb, kb, vtb, yb);

    // 3) output projection -> d_out fp32
    gemm_mfma<0><<<dim3(NP_PRJ_ / 128, M_ / 128), 256, 0, stream>>>(
        (const unsigned short*)yb, (const unsigned short*)wtp, b_proj,
        out, nullptr, nullptr, nullptr);
}

// Round 4
// 210.508 us; speedup vs baseline: 12.6977x; 1.2785x over previous
//
#include <hip/hip_runtime.h>
#include <hip/hip_bf16.h>

#define B_   16
#define T_   512
#define C_   1080
#define H_   20
#define HD_  54
#define DP_  64                 // padded head dim
#define M_   (B_ * T_)          // 8192
#define KP_  1088               // padded K (17*64)
#define NT_  17                 // K tiles of 64
#define NQKV_ 3840              // padded 3C: 3 * 20 * 64  (30 * 128)
#define NPRJ_ 1152              // padded C (9*128)
#define NBT_ (B_ * H_ * T_)     // 163840

typedef short bf16x8 __attribute__((ext_vector_type(8)));
typedef float f32x4  __attribute__((ext_vector_type(4)));
typedef unsigned short u16x8 __attribute__((ext_vector_type(8)));

__device__ __forceinline__ void gload_lds16(const void* g, void* l) {
    __builtin_amdgcn_global_load_lds(
        (const __attribute__((address_space(1))) void*)g,
        (__attribute__((address_space(3))) void*)l,
        16, 0, 0);
}

// ---------------------------------------------------------------------------
// x [8192][1080] fp32 -> xb [8192][1088] bf16, zero-padded.
// ---------------------------------------------------------------------------
__global__ __launch_bounds__(256) void cvt_pad(
    const float* __restrict__ src, __hip_bfloat16* __restrict__ dst)
{
    int idx = blockIdx.x * 256 + threadIdx.x;
    if (idx >= M_ * (KP_ / 4)) return;
    int m = idx / (KP_ / 4), c = idx - m * (KP_ / 4);
    ushort4 o;
    if (c < C_ / 4) {
        float4 v = *reinterpret_cast<const float4*>(src + (size_t)m * C_ + c * 4);
        o.x = __builtin_bit_cast(unsigned short, __float2bfloat16(v.x));
        o.y = __builtin_bit_cast(unsigned short, __float2bfloat16(v.y));
        o.z = __builtin_bit_cast(unsigned short, __float2bfloat16(v.z));
        o.w = __builtin_bit_cast(unsigned short, __float2bfloat16(v.w));
    } else {
        o.x = o.y = o.z = o.w = 0;
    }
    *reinterpret_cast<ushort4*>(reinterpret_cast<unsigned short*>(dst) + (size_t)m * KP_ + c * 4) = o;
}

// ---------------------------------------------------------------------------
// W_attn [1080][3240] fp32 -> wta [3840][1088] bf16: transposed, head-PADDED:
// n' = which*1280 + h*64 + d  <-  src col which*1080 + h*54 + d (d<54), else 0.
// ---------------------------------------------------------------------------
__global__ __launch_bounds__(256) void transpose_wqkv(
    const float* __restrict__ W, __hip_bfloat16* __restrict__ Wt)
{
    __shared__ float tile[32][33];
    int n0 = blockIdx.x * 32, k0 = blockIdx.y * 32;
    int tx = threadIdx.x, ty = threadIdx.y;
    int np = n0 + tx;
    int which = np / 1280;
    int rem = np - which * 1280;
    int h = rem >> 6, d = rem & 63;
    int sn = which * C_ + h * HD_ + d;
    bool valid = d < HD_;
    #pragma unroll
    for (int i = 0; i < 32; i += 8) {
        int k = k0 + ty + i;
        tile[ty + i][tx] = (valid && k < C_) ? W[(size_t)k * (3 * C_) + sn] : 0.f;
    }
    __syncthreads();
    #pragma unroll
    for (int i = 0; i < 32; i += 8) {
        int n = n0 + ty + i, k = k0 + tx;
        Wt[(size_t)n * KP_ + k] = __float2bfloat16(tile[tx][ty + i]);
    }
}

// ---------------------------------------------------------------------------
// W_proj [1080][1080] fp32 -> wtp [1152][1088] bf16, transposed zero-padded.
// ---------------------------------------------------------------------------
__global__ __launch_bounds__(256) void transpose_w(
    const float* __restrict__ W, __hip_bfloat16* __restrict__ Wt,
    int K, int N, int Kp)
{
    __shared__ float tile[32][33];
    int n0 = blockIdx.x * 32, k0 = blockIdx.y * 32;
    int tx = threadIdx.x, ty = threadIdx.y;
    #pragma unroll
    for (int i = 0; i < 32; i += 8) {
        int k = k0 + ty + i, n = n0 + tx;
        tile[ty + i][tx] = (k < K && n < N) ? W[(size_t)k * N + n] : 0.f;
    }
    __syncthreads();
    #pragma unroll
    for (int i = 0; i < 32; i += 8) {
        int n = n0 + ty + i, k = k0 + tx;
        Wt[(size_t)n * Kp + k] = __float2bfloat16(tile[tx][ty + i]);
    }
}

// ---------------------------------------------------------------------------
// padded QKV bias: bp[3840], zeros on d>=54 pads.
// ---------------------------------------------------------------------------
__global__ __launch_bounds__(256) void build_bias(
    const float* __restrict__ b_attn, float* __restrict__ bp)
{
    int i = blockIdx.x * 256 + threadIdx.x;
    if (i < NQKV_) {
        int which = i / 1280, rem = i - which * 1280;
        int h = rem >> 6, d = rem & 63;
        bp[i] = (d < HD_) ? b_attn[which * C_ + h * HD_ + d] : 0.f;
    }
}

// ---------------------------------------------------------------------------
// bf16 MFMA GEMM: 128x128 tile, BK=64, 4 waves; ring-2 LDS (2x32KB) with
// counted s_waitcnt vmcnt(8) (loads fly across barriers), raw s_barrier.
// XCD-chunked block swizzle (grid %8 == 0).
// MODE 0: outP[m*1080+n] = acc + bias[n] (fp32), n<1080 guarded.
// MODE 1: head-padded qkv: q,k -> [bh][t][64] direct; v -> [bh][64][t] via
//         skew-swizzled LDS transpose + 16B coalesced stores.
// ---------------------------------------------------------------------------
template<int MODE>
__global__ __launch_bounds__(256) void gemm_mfma(
    const unsigned short* __restrict__ A,
    const unsigned short* __restrict__ Bt,
    const float* __restrict__ bias,
    float* __restrict__ outP,
    unsigned short* __restrict__ outQ,
    unsigned short* __restrict__ outK,
    unsigned short* __restrict__ outV)
{
    __shared__ __align__(16) char smem[65536];

    const int tid  = threadIdx.x;
    const int lane = tid & 63;
    const int wv   = tid >> 6;
    const int wm   = (wv >> 1) * 64;
    const int wn   = (wv & 1) * 64;
    const int lr   = lane & 15;
    const int lk   = lane >> 4;

    const int gx  = gridDim.x;
    const int nwg = gx * gridDim.y;
    const int id  = blockIdx.y * gx + blockIdx.x;
    const int cpx = nwg >> 3;
    const int swz = (id & 7) * cpx + (id >> 3);
    const int m0 = (swz / gx) * 128;
    const int n0 = (swz % gx) * 128;

    f32x4 acc[4][4] = {};

    auto stage = [&](int buf, int kt) {
        const int k0 = kt * 64;
        char* sb = smem + buf * 32768;
        #pragma unroll
        for (int it = 0; it < 4; ++it) {
            int ci = it * 256 + tid;
            int r = ci >> 3, p = ci & 7;
            int kc = p ^ (r & 7);
            gload_lds16(A + (size_t)(m0 + r) * KP_ + k0 + kc * 8, sb + ci * 16);
        }
        #pragma unroll
        for (int it = 0; it < 4; ++it) {
            int ci = it * 256 + tid;
            int r = ci >> 3, p = ci & 7;
            int kc = p ^ (r & 7);
            gload_lds16(Bt + (size_t)(n0 + r) * KP_ + k0 + kc * 8, sb + 16384 + ci * 16);
        }
    };

    stage(0, 0);
    for (int kt = 0; kt < NT_; ++kt) {
        const int c = kt & 1;
        if (kt + 1 < NT_) {
            stage(1 - c, kt + 1);
            asm volatile("s_waitcnt vmcnt(8)" ::: "memory");
        } else {
            asm volatile("s_waitcnt vmcnt(0)" ::: "memory");
        }
        __builtin_amdgcn_s_barrier();
        asm volatile("" ::: "memory");

        const char* base = smem + c * 32768;
        #pragma unroll
        for (int kk = 0; kk < 2; ++kk) {
            bf16x8 af[4], bfr[4];
            #pragma unroll
            for (int mi = 0; mi < 4; ++mi) {
                int row = wm + mi * 16 + lr;
                int cp  = (kk * 4 + lk) ^ (row & 7);
                af[mi] = *reinterpret_cast<const bf16x8*>(base + row * 128 + cp * 16);
            }
            #pragma unroll
            for (int ni = 0; ni < 4; ++ni) {
                int row = wn + ni * 16 + lr;
                int cp  = (kk * 4 + lk) ^ (row & 7);
                bfr[ni] = *reinterpret_cast<const bf16x8*>(base + 16384 + row * 128 + cp * 16);
            }
            #pragma unroll
            for (int mi = 0; mi < 4; ++mi)
                #pragma unroll
                for (int ni = 0; ni < 4; ++ni)
                    acc[mi][ni] = __builtin_amdgcn_mfma_f32_16x16x32_bf16(
                        af[mi], bfr[ni], acc[mi][ni], 0, 0, 0);
        }
        asm volatile("" ::: "memory");
        __builtin_amdgcn_s_barrier();
    }

    if constexpr (MODE == 0) {
        #pragma unroll
        for (int mi = 0; mi < 4; ++mi) {
            int mrow = m0 + wm + mi * 16 + lk * 4;
            #pragma unroll
            for (int ni = 0; ni < 4; ++ni) {
                int n = n0 + wn + ni * 16 + lr;
                if (n < C_) {
                    float bs = bias[n];
                    #pragma unroll
                    for (int j = 0; j < 4; ++j)
                        outP[(size_t)(mrow + j) * C_ + n] = acc[mi][ni][j] + bs;
                }
            }
        }
    } else {
        const int which = n0 / 1280;     // block-uniform: 0=q, 1=k, 2=v
        if (which < 2) {
            unsigned short* dst = which ? outK : outQ;
            #pragma unroll
            for (int mi = 0; mi < 4; ++mi) {
                int mg = m0 + wm + mi * 16 + lk * 4;
                int b = mg >> 9, t0 = mg & (T_ - 1);
                #pragma unroll
                for (int ni = 0; ni < 4; ++ni) {
                    int nl = wn + ni * 16 + lr;
                    int ng = n0 + nl - which * 1280;
                    int h = ng >> 6, d = ng & 63;
                    float bs = bias[n0 + nl];
                    size_t basei = ((size_t)(b * H_ + h) * T_ + t0) * DP_ + d;
                    #pragma unroll
                    for (int j = 0; j < 4; ++j)
                        dst[basei + (size_t)j * DP_] = __builtin_bit_cast(unsigned short,
                            __float2bfloat16(acc[mi][ni][j] + bs));
                }
            }
        } else {
            // V: transpose 128x128 tile in LDS (skew-swizzled), 16B stores.
            unsigned short* lt = (unsigned short*)smem;   // [128 n][136 m], skewed
            #pragma unroll
            for (int mi = 0; mi < 4; ++mi) {
                int ml = wm + mi * 16 + lk * 4;
                int mc = ml >> 3, mo = ml & 7;
                #pragma unroll
                for (int ni = 0; ni < 4; ++ni) {
                    int nl = wn + ni * 16 + lr;
                    float bs = bias[n0 + nl];
                    ushort4 pk;
                    pk.x = __builtin_bit_cast(unsigned short, __float2bfloat16(acc[mi][ni][0] + bs));
                    pk.y = __builtin_bit_cast(unsigned short, __float2bfloat16(acc[mi][ni][1] + bs));
                    pk.z = __builtin_bit_cast(unsigned short, __float2bfloat16(acc[mi][ni][2] + bs));
                    pk.w = __builtin_bit_cast(unsigned short, __float2bfloat16(acc[mi][ni][3] + bs));
                    int slot = mc ^ ((nl >> 3) & 15);
                    *reinterpret_cast<ushort4*>(lt + nl * 136 + slot * 8 + mo) = pk;
                }
            }
            __syncthreads();
            #pragma unroll
            for (int it = 0; it < 8; ++it) {
                int idx = it * 256 + tid;            // 2048 chunk tasks
                int c2 = idx >> 4, j = idx & 15;     // c2: n-row, j: m-chunk
                int slot = j ^ ((c2 >> 3) & 15);
                u16x8 v = *reinterpret_cast<const u16x8*>(lt + c2 * 136 + slot * 8);
                int ng = n0 + c2 - 2560;
                int h = ng >> 6, d = ng & 63;
                int mg = m0 + j * 8;
                int b = mg >> 9, t = mg & (T_ - 1);
                *reinterpret_cast<u16x8*>(outV + ((size_t)(b * H_ + h) * DP_ + d) * T_ + t) = v;
            }
        }
    }
}

// ---------------------------------------------------------------------------
// MFMA flash attention. grid: (T/64, B*H). 256 threads = 4 waves x 16 q-rows.
// Q,K: [bh][t][64] bf16; Vt: [bh][64][t] bf16; Y: [b*T][1088] bf16.
// ---------------------------------------------------------------------------
__global__ __launch_bounds__(256) void attn_mfma(
    const unsigned short* __restrict__ Q, const unsigned short* __restrict__ K,
    const unsigned short* __restrict__ Vt, __hip_bfloat16* __restrict__ Y)
{
    __shared__ __align__(16) char kvs[16384];
    __shared__ __align__(16) unsigned short ps[4][16][72];

    const int tid  = threadIdx.x;
    const int lane = tid & 63;
    const int wv   = tid >> 6;
    const int lq   = lane & 15;
    const int lg   = lane >> 4;
    const int bh   = blockIdx.y;
    const int qt   = blockIdx.x;
    const int qbase = qt * 64;
    const float scale = 0.13608276348795434f;  // 1/sqrt(54)

    bf16x8 qf[2];
    {
        const unsigned short* qp = Q + ((size_t)bh * T_ + qbase + wv * 16 + lq) * DP_;
        qf[0] = *reinterpret_cast<const bf16x8*>(qp + lg * 8);
        qf[1] = *reinterpret_cast<const bf16x8*>(qp + 32 + lg * 8);
    }

    f32x4 o[4] = {};
    f32x4 m_run, l_run;
    #pragma unroll
    for (int j = 0; j < 4; ++j) { m_run[j] = -3.0e38f; l_run[j] = 0.f; }

    unsigned short* pbase = &ps[wv][0][0];

    const int nt = qt + 1;
    for (int kt = 0; kt < nt; ++kt) {
        const int kbase = kt * 64;
        {
            const unsigned short* kgp = K  + ((size_t)bh * T_ + kbase) * DP_;
            const unsigned short* vgp = Vt + (size_t)bh * DP_ * T_ + kbase;
            #pragma unroll
            for (int it = 0; it < 2; ++it) {
                int ci = it * 256 + tid;
                int r = ci >> 3, p = ci & 7;
                int pc = p ^ (r & 7);
                gload_lds16(kgp + (size_t)r * DP_ + pc * 8, kvs + ci * 16);
            }
            #pragma unroll
            for (int it = 0; it < 2; ++it) {
                int ci = it * 256 + tid;
                int r = ci >> 3, p = ci & 7;
                int pc = p ^ (r & 7);
                gload_lds16(vgp + (size_t)r * T_ + pc * 8, kvs + 8192 + ci * 16);
            }
        }
        __syncthreads();

        f32x4 s[4] = {};
        #pragma unroll
        for (int dc = 0; dc < 2; ++dc) {
            #pragma unroll
            for (int ni = 0; ni < 4; ++ni) {
                int row = ni * 16 + lq;
                int ch  = (dc * 4 + lg) ^ (row & 7);
                bf16x8 kf = *reinterpret_cast<const bf16x8*>(kvs + row * 128 + ch * 16);
                s[ni] = __builtin_amdgcn_mfma_f32_16x16x32_bf16(qf[dc], kf, s[ni], 0, 0, 0);
            }
        }

        f32x4 mloc;
        #pragma unroll
        for (int j = 0; j < 4; ++j) mloc[j] = -3.0e38f;
        #pragma unroll
        for (int ni = 0; ni < 4; ++ni) {
            int kg = kbase + ni * 16 + lq;
            #pragma unroll
            for (int j = 0; j < 4; ++j) {
                int qg = qbase + wv * 16 + lg * 4 + j;
                float sv = s[ni][j] * scale;
                sv = (kg > qg) ? -3.0e38f : sv;
                s[ni][j] = sv;
                mloc[j] = fmaxf(mloc[j], sv);
            }
        }
        #pragma unroll
        for (int x = 1; x < 16; x <<= 1)
            #pragma unroll
            for (int j = 0; j < 4; ++j)
                mloc[j] = fmaxf(mloc[j], __shfl_xor(mloc[j], x));

        f32x4 corr, lsum;
        #pragma unroll
        for (int j = 0; j < 4; ++j) {
            float mn = fmaxf(m_run[j], mloc[j]);
            corr[j]  = __expf(m_run[j] - mn);
            m_run[j] = mn;
            lsum[j]  = 0.f;
        }
        #pragma unroll
        for (int ni = 0; ni < 4; ++ni) {
            #pragma unroll
            for (int j = 0; j < 4; ++j) {
                float p = __expf(s[ni][j] - m_run[j]);
                lsum[j] += p;
                int qr = lg * 4 + j;
                int cidx = (ni * 2 + (lq >> 3)) ^ (qr & 7);
                pbase[qr * 72 + cidx * 8 + (lq & 7)] =
                    __builtin_bit_cast(unsigned short, __float2bfloat16(p));
            }
        }
        #pragma unroll
        for (int x = 1; x < 16; x <<= 1)
            #pragma unroll
            for (int j = 0; j < 4; ++j)
                lsum[j] += __shfl_xor(lsum[j], x);
        #pragma unroll
        for (int j = 0; j < 4; ++j)
            l_run[j] = l_run[j] * corr[j] + lsum[j];
        #pragma unroll
        for (int ni = 0; ni < 4; ++ni)
            #pragma unroll
            for (int j = 0; j < 4; ++j)
                o[ni][j] *= corr[j];

        asm volatile("s_waitcnt lgkmcnt(0)" ::: "memory");
        __builtin_amdgcn_sched_barrier(0);

        #pragma unroll
        for (int dc = 0; dc < 2; ++dc) {
            int cc = (dc * 4 + lg) ^ (lq & 7);
            bf16x8 pf = *reinterpret_cast<const bf16x8*>(pbase + lq * 72 + cc * 8);
            #pragma unroll
            for (int ni = 0; ni < 4; ++ni) {
                int row = ni * 16 + lq;
                int ch  = (dc * 4 + lg) ^ (row & 7);
                bf16x8 vf = *reinterpret_cast<const bf16x8*>(kvs + 8192 + row * 128 + ch * 16);
                o[ni] = __builtin_amdgcn_mfma_f32_16x16x32_bf16(pf, vf, o[ni], 0, 0, 0);
            }
        }
        __syncthreads();
    }

    const int b = bh / H_, h = bh - b * H_;
    #pragma unroll
    for (int j = 0; j < 4; ++j) {
        float inv = 1.f / l_run[j];
        int t = qbase + wv * 16 + lg * 4 + j;
        #pragma unroll
        for (int ni = 0; ni < 4; ++ni) {
            int d = ni * 16 + lq;
            if (d < HD_)
                Y[((size_t)b * T_ + t) * KP_ + h * HD_ + d] =
                    __float2bfloat16(o[ni][j] * inv);
        }
    }
}

// ---------------------------------------------------------------------------
extern "C" void kernel_launch(void* const* d_in, const int* in_sizes, int n_in,
                              void* d_out, int out_size, void* d_ws, size_t ws_size,
                              hipStream_t stream)
{
    const float* x      = (const float*)d_in[0];
    const float* W_attn = (const float*)d_in[1];
    const float* b_attn = (const float*)d_in[2];
    const float* W_proj = (const float*)d_in[3];
    const float* b_proj = (const float*)d_in[4];
    float* out = (float*)d_out;

    __hip_bfloat16* xb = (__hip_bfloat16*)d_ws;                        // [8192][1088]
    unsigned short* qb = (unsigned short*)(xb + (size_t)M_ * KP_);     // [bh][t][64]
    unsigned short* kb = qb + (size_t)NBT_ * DP_;
    unsigned short* vtb = kb + (size_t)NBT_ * DP_;                     // [bh][64][t]
    __hip_bfloat16* wta = (__hip_bfloat16*)(vtb + (size_t)NBT_ * DP_); // [3840][1088]
    __hip_bfloat16* wtp = wta + (size_t)NQKV_ * KP_;                   // [1152][1088]
    float* bp = (float*)(wtp + (size_t)NPRJ_ * KP_);                   // [3840]
    __hip_bfloat16* yb = xb;   // alias: x fully consumed before attn writes y

    cvt_pad<<<(M_ * (KP_ / 4) + 255) / 256, 256, 0, stream>>>(x, xb);
    transpose_wqkv<<<dim3(NQKV_ / 32, KP_ / 32), dim3(32, 8), 0, stream>>>(W_attn, wta);
    transpose_w<<<dim3(NPRJ_ / 32, KP_ / 32), dim3(32, 8), 0, stream>>>(
        W_proj, wtp, C_, C_, KP_);
    build_bias<<<(NQKV_ + 255) / 256, 256, 0, stream>>>(b_attn, bp);

    // 1) QKV projection (head-padded N'=3840) -> q/k [bh][t][64], v [bh][64][t]
    gemm_mfma<1><<<dim3(NQKV_ / 128, M_ / 128), 256, 0, stream>>>(
        (const unsigned short*)xb, (const unsigned short*)wta, bp,
        nullptr, qb, kb, vtb);

    // 2) MFMA flash attention -> yb (= xb; pad cols stay zero)
    attn_mfma<<<dim3(T_ / 64, B_ * H_), 256, 0, stream>>>(qb, kb, vtb, yb);

    // 3) output projection -> d_out fp32
    gemm_mfma<0><<<dim3(NPRJ_ / 128, M_ / 128), 256, 0, stream>>>(
        (const unsigned short*)yb, (const unsigned short*)wtp, b_proj,
        out, nullptr, nullptr, nullptr);
}